// Round 13
// baseline (96.516 us; speedup 1.0000x reference)
//
#include <hip/hip_runtime.h>
#include <hip/hip_bf16.h>
#include <cstdint>

#define N_NODES 8192
#define F_IN    512
#define D_O     64
#define H_N     8
#define NOUT    512   // H_N * D_O
#define MAXD    128   // max supported degree (mean ~33.8, sigma 5.7 -> 16 sigma)

#define BM 64
#define BN 128
#define BK 64

typedef __attribute__((ext_vector_type(8))) short short8;
typedef __attribute__((ext_vector_type(4))) float f32x4;

static __device__ __forceinline__ ushort f2bf(float f) {
  union { float f; uint32_t u; } v; v.f = f;
  uint32_t r = v.u + 0x7FFFu + ((v.u >> 16) & 1u);  // RNE
  return (ushort)(r >> 16);
}
static __device__ __forceinline__ float bf2f(ushort u) {
  union { uint32_t u; float f; } v; v.u = ((uint32_t)u) << 16;
  return v.f;
}

// ---------------------------------------------------------------------------
// Kernel 0: Wt[h][d][k] = bf16(W[h][k][d]) via LDS tile (64 blocks only)
// ---------------------------------------------------------------------------
__global__ __launch_bounds__(256) void convert_wt(const float* __restrict__ W,
                                                  ushort* __restrict__ Wt) {
  __shared__ float Ws[64][65];
  const int bb = blockIdx.x;                   // 64 blocks = 8 heads x 8 k-tiles
  const int t  = threadIdx.x;
  const int h = bb >> 3, kt = bb & 7;
  const int d = t & 63, krg = (t >> 6) * 16;
  const float* src = &W[((size_t)h * F_IN + kt * 64 + krg) * D_O + d];
  #pragma unroll
  for (int q = 0; q < 16; ++q)
    Ws[krg + q][d] = src[(size_t)q * D_O];     // coalesced over d
  __syncthreads();
  const int d0 = t >> 2, kq = (t & 3) * 16;
  ushort* dst = &Wt[(size_t)h * D_O * F_IN + (size_t)d0 * F_IN + kt * 64 + kq];
  #pragma unroll
  for (int q = 0; q < 16; ++q)
    dst[q] = f2bf(Ws[kq + q][d0]);             // coalesced over k
}

// ---------------------------------------------------------------------------
// Kernel 1: pure adj-row scan -> CSR. 16 B LDS -> full 32 waves/CU streaming.
// ---------------------------------------------------------------------------
__global__ __launch_bounds__(256) void scan(const uint32_t* __restrict__ adj,
                                            int* __restrict__ nbr_g,
                                            int* __restrict__ deg_g) {
  __shared__ int wsum[4];
  const int i    = blockIdx.x;
  const int tid  = threadIdx.x;
  const int lane = tid & 63;
  const int wv   = tid >> 6;

  const uint32_t* arow = adj + (size_t)i * N_NODES;
  uint32_t bits = 0;
  #pragma unroll
  for (int u = 0; u < 8; ++u) {
    const uint4 a = *(const uint4*)&arow[(u * 256 + tid) * 4];
    if (a.x) bits |= 1u << (u * 4 + 0);
    if (a.y) bits |= 1u << (u * 4 + 1);
    if (a.z) bits |= 1u << (u * 4 + 2);
    if (a.w) bits |= 1u << (u * 4 + 3);
  }
  const int cnt = __popc(bits);
  int v = cnt;
  #pragma unroll
  for (int o = 1; o < 64; o <<= 1) {
    int u = __shfl_up(v, o);
    if (lane >= o) v += u;
  }
  if (lane == 63) wsum[wv] = v;
  __syncthreads();
  int base = 0, total = 0;
  #pragma unroll
  for (int ww = 0; ww < 4; ++ww) {
    int s = wsum[ww];
    if (ww < wv) base += s;
    total += s;
  }
  int off = base + v - cnt;
  #pragma unroll
  for (int u = 0; u < 8; ++u)
    #pragma unroll
    for (int bq = 0; bq < 4; ++bq)
      if (bits & (1u << (u * 4 + bq))) {
        if (off < MAXD) nbr_g[(size_t)i * MAXD + off] = (u * 256 + tid) * 4 + bq;
        ++off;
      }
  if (tid == 0) deg_g[i] = min(total, MAXD);
}

// ---------------------------------------------------------------------------
// Kernel 2: Whb = bf16(x @ Wt^T) + fused f1/f2. A staged directly from x f32
// (in-register f2bf), B from Wt bf16. 64x128 tile, BK=64, 512 blocks.
// ---------------------------------------------------------------------------
__global__ __launch_bounds__(256) void gemm_f(const float* __restrict__ x,
                                              const ushort* __restrict__ Wt,
                                              const float* __restrict__ a1,
                                              const float* __restrict__ a2,
                                              ushort* __restrict__ Whb,
                                              float* __restrict__ f1,
                                              float* __restrict__ f2) {
  __shared__ ushort As[BM][BK + 8];
  __shared__ ushort Bs[BN][BK + 8];

  const int tid  = threadIdx.x;
  const int lane = tid & 63;
  const int wv   = tid >> 6;
  const int wr   = wv >> 1, wc = wv & 1;
  const int r0   = blockIdx.y * BM;
  const int c0   = blockIdx.x * BN;
  const int lm   = lane & 15;
  const int lg   = lane >> 4;

  f32x4 acc[2][4];
  #pragma unroll
  for (int m2 = 0; m2 < 2; ++m2)
    #pragma unroll
    for (int n2 = 0; n2 < 4; ++n2)
      acc[m2][n2] = (f32x4){0.f, 0.f, 0.f, 0.f};

  for (int k0 = 0; k0 < F_IN; k0 += BK) {
    __syncthreads();
    #pragma unroll
    for (int p = 0; p < 4; ++p) {                // A: 64x64 f32 = 1024 float4
      const int e = p * 256 + tid;
      const int row = e >> 4, q4 = (e & 15) * 4;
      const float4 v = *(const float4*)&x[(size_t)(r0 + row) * F_IN + k0 + q4];
      ushort4 u;
      u.x = f2bf(v.x); u.y = f2bf(v.y); u.z = f2bf(v.z); u.w = f2bf(v.w);
      *(ushort4*)&As[row][q4] = u;
    }
    #pragma unroll
    for (int p = 0; p < 4; ++p) {                // B: 128x64 bf16 = 1024 short8
      const int e = p * 256 + tid;
      const int row = e >> 3, ck = (e & 7) * 8;
      *(short8*)&Bs[row][ck] = *(const short8*)&Wt[(size_t)(c0 + row) * F_IN + k0 + ck];
    }
    __syncthreads();

    #pragma unroll
    for (int kk = 0; kk < 2; ++kk) {
      const int koff = kk * 32 + lg * 8;
      short8 af[2], bf[4];
      #pragma unroll
      for (int m2 = 0; m2 < 2; ++m2)
        af[m2] = *(const short8*)&As[wr * 32 + m2 * 16 + lm][koff];
      #pragma unroll
      for (int n2 = 0; n2 < 4; ++n2)
        bf[n2] = *(const short8*)&Bs[wc * 64 + n2 * 16 + lm][koff];
      #pragma unroll
      for (int m2 = 0; m2 < 2; ++m2)
        #pragma unroll
        for (int n2 = 0; n2 < 4; ++n2)
          acc[m2][n2] = __builtin_amdgcn_mfma_f32_16x16x32_bf16(af[m2], bf[n2], acc[m2][n2], 0, 0, 0);
    }
  }

  // ---- epilogue: Whb write + fused f1/f2 --------------------------------
  const int head = (c0 >> 6) + wc;               // bx*2 + wc
  float a1v[4], a2v[4];
  #pragma unroll
  for (int n2 = 0; n2 < 4; ++n2) {
    a1v[n2] = a1[head * D_O + n2 * 16 + lm];
    a2v[n2] = a2[head * D_O + n2 * 16 + lm];
  }
  #pragma unroll
  for (int m2 = 0; m2 < 2; ++m2) {
    #pragma unroll
    for (int r = 0; r < 4; ++r) {
      const int row = r0 + wr * 32 + m2 * 16 + lg * 4 + r;
      float p1 = 0.f, p2 = 0.f;
      #pragma unroll
      for (int n2 = 0; n2 < 4; ++n2) {
        const float v = acc[m2][n2][r];
        p1 += v * a1v[n2];
        p2 += v * a2v[n2];
        Whb[(size_t)row * NOUT + c0 + wc * 64 + n2 * 16 + lm] = f2bf(v);
      }
      #pragma unroll
      for (int o = 1; o < 16; o <<= 1) {
        p1 += __shfl_xor(p1, o);
        p2 += __shfl_xor(p2, o);
      }
      if (lm == 0) {
        f1[(size_t)row * H_N + head] = p1;
        f2[(size_t)row * H_N + head] = p2;
      }
    }
  }
}

// ---------------------------------------------------------------------------
// Kernel 3: panel attention, 128-thr blocks = 2 waves; wave w processes row
// 2*rpair+w of panel P independently (same barrier count both waves).
// 16 blocks/CU x 2 waves = 32 waves/CU for the latency-bound gather.
// ---------------------------------------------------------------------------
__global__ __launch_bounds__(128) void gat_panel(const int* __restrict__ nbr_g,
                                                 const int* __restrict__ deg_g,
                                                 const ushort* __restrict__ Whb,
                                                 const float* __restrict__ f1,
                                                 const float* __restrict__ f2,
                                                 float* __restrict__ out) {
  const int bid = blockIdx.x;
  const int P   = bid >> 12;      // panel 0..3 (4096 blocks per panel)
  const int rp  = bid & 4095;
  const int w   = threadIdx.x >> 6;   // wave -> row select
  const int i   = rp * 2 + w;
  const int t   = threadIdx.x & 63;   // lane

  __shared__ int   nbr[2][MAXD];
  __shared__ float ff[2][MAXD][2];
  __shared__ float ps[2][MAXD][2];
  __shared__ float f1s2[2][2], invs2[2][2];

  const int deg = deg_g[i];
  if (t < deg)      nbr[w][t]      = nbr_g[(size_t)i * MAXD + t];
  if (t + 64 < deg) nbr[w][t + 64] = nbr_g[(size_t)i * MAXD + t + 64];
  if (t < 2) f1s2[w][t] = f1[(size_t)i * H_N + 2 * P + t];
  __syncthreads();

  // f2 pair gather (both heads of this panel in one 8-B load)
  for (int n = t; n < deg; n += 64) {
    const float2 v = *(const float2*)&f2[(size_t)nbr[w][n] * H_N + 2 * P];
    ff[w][n][0] = v.x; ff[w][n][1] = v.y;
  }
  __syncthreads();

  // softmax: lanes [0,32) -> head 0, [32,64) -> head 1 (xor <=16 stays in-half)
  {
    const int h = t >> 5;
    const int l = t & 31;
    const float f1v = f1s2[w][h];
    float m = -3.0e38f;
    for (int n = l; n < deg; n += 32) {
      float e = f1v + ff[w][n][h];
      e = e > 0.f ? e : 0.2f * e;
      ps[w][n][h] = e;
      m = fmaxf(m, e);
    }
    #pragma unroll
    for (int o = 16; o; o >>= 1) m = fmaxf(m, __shfl_xor(m, o));
    float s = 0.f;
    for (int n = l; n < deg; n += 32) {
      const float e = __expf(ps[w][n][h] - m);
      ps[w][n][h] = e;
      s += e;
    }
    #pragma unroll
    for (int o = 16; o; o >>= 1) s += __shfl_xor(s, o);
    if (l == 0) invs2[w][h] = 1.0f / s;
  }
  __syncthreads();

  // gather/accumulate: lane t owns panel cols {2t, 2t+1}; head = t>>5
  const int ht      = t >> 5;
  const int colbase = P * 128 + t * 2;
  float a0 = 0.f, a1c = 0.f;
  #pragma unroll 8
  for (int n = 0; n < deg; ++n) {
    const float pv = ps[w][n][ht];
    const ushort2 u = *(const ushort2*)&Whb[(size_t)nbr[w][n] * NOUT + colbase];
    a0  += pv * bf2f(u.x);
    a1c += pv * bf2f(u.y);
  }
  const float inv = invs2[w][ht];
  float2 o2; o2.x = a0 * inv; o2.y = a1c * inv;
  *(float2*)&out[(size_t)i * NOUT + colbase] = o2;
}

extern "C" void kernel_launch(void* const* d_in, const int* in_sizes, int n_in,
                              void* d_out, int out_size, void* d_ws, size_t ws_size,
                              hipStream_t stream) {
  const float* x   = (const float*)d_in[0];
  const float* adj = (const float*)d_in[1];
  const float* W   = (const float*)d_in[2];
  const float* a1  = (const float*)d_in[3];
  const float* a2  = (const float*)d_in[4];
  float* out = (float*)d_out;

  ushort* Whb = (ushort*)d_ws;                          // 4M bf16 = 8 MB
  ushort* Wt  = Whb + (size_t)N_NODES * NOUT;           // 256K bf16 = 0.5 MB
  float*  f1  = (float*)(Wt + (size_t)H_N * D_O * F_IN);
  float*  f2  = f1 + (size_t)N_NODES * H_N;
  int*    nbr_g = (int*)(f2 + (size_t)N_NODES * H_N);   // 8192*128*4 = 4 MB
  int*    deg_g = nbr_g + (size_t)N_NODES * MAXD;       // 32 KB

  hipLaunchKernelGGL(convert_wt, dim3(64), dim3(256), 0, stream, W, Wt);
  hipLaunchKernelGGL(scan, dim3(N_NODES), dim3(256), 0, stream,
                     (const uint32_t*)adj, nbr_g, deg_g);
  hipLaunchKernelGGL(gemm_f, dim3(NOUT / BN, N_NODES / BM), dim3(256), 0, stream,
                     x, Wt, a1, a2, Whb, f1, f2);
  hipLaunchKernelGGL(gat_panel, dim3(4 * N_NODES / 2), dim3(128), 0, stream,
                     nbr_g, deg_g, Whb, f1, f2, out);
}